// Round 1
// baseline (4799.218 us; speedup 1.0000x reference)
//
#include <hip/hip_runtime.h>
#include <hip/hip_bf16.h>

#define HIDDEN 4096
#define NH 32
#define NKV 8
#define HD 128
#define LCK 3
#define BB 2
#define SS 1024
#define MTOT (BB * SS)  // 2048

// ---------------------------------------------------------------------------
// fp32 tiled GEMM: C[M,N] = A[M,K] @ B[K,N], all row-major.
// 64x64 output tile per block, 256 threads, 4x4 accum per thread, K-tile 16.
// ---------------------------------------------------------------------------
#define TILE 64
#define KT 16

__global__ __launch_bounds__(256) void gemm_f32(
    const float* __restrict__ A, const float* __restrict__ B,
    float* __restrict__ C, int M, int N, int K) {
  __shared__ float As[KT][TILE + 4];  // +4 pad: write conflicts reduce to free 2-way
  __shared__ float Bs[KT][TILE];

  const int t = threadIdx.x;
  const int bm = blockIdx.y * TILE;
  const int bn = blockIdx.x * TILE;
  const int r4 = (t >> 4) * 4;  // 0,4,..,60 row group
  const int c4 = (t & 15) * 4;  // 0,4,..,60 col group

  // A staging: thread loads A[bm+ai][k0+aj .. +3]
  const int ai = t >> 2;        // 0..63
  const int aj = (t & 3) * 4;   // 0,4,8,12
  // B staging: thread loads B[k0+bj][bn+bn4 .. +3]
  const int bj = t >> 4;        // 0..15
  const int bn4 = (t & 15) * 4; // 0..60

  const float* Aptr = A + (size_t)(bm + ai) * K + aj;
  const float* Bptr = B + (size_t)bj * N + bn + bn4;

  float acc[4][4];
#pragma unroll
  for (int i = 0; i < 4; ++i)
#pragma unroll
    for (int j = 0; j < 4; ++j) acc[i][j] = 0.0f;

  for (int k0 = 0; k0 < K; k0 += KT) {
    float4 av = *(const float4*)(Aptr + k0);
    float4 bv = *(const float4*)(Bptr + (size_t)k0 * N);
    As[aj + 0][ai] = av.x;
    As[aj + 1][ai] = av.y;
    As[aj + 2][ai] = av.z;
    As[aj + 3][ai] = av.w;
    *(float4*)&Bs[bj][bn4] = bv;
    __syncthreads();
#pragma unroll
    for (int kk = 0; kk < KT; ++kk) {
      float a[4], b[4];
      *(float4*)a = *(const float4*)&As[kk][r4];
      *(float4*)b = *(const float4*)&Bs[kk][c4];
#pragma unroll
      for (int ii = 0; ii < 4; ++ii)
#pragma unroll
        for (int jj = 0; jj < 4; ++jj)
          acc[ii][jj] = fmaf(a[ii], b[jj], acc[ii][jj]);
    }
    __syncthreads();
  }

#pragma unroll
  for (int ii = 0; ii < 4; ++ii) {
    float4 o = make_float4(acc[ii][0], acc[ii][1], acc[ii][2], acc[ii][3]);
    *(float4*)(C + (size_t)(bm + r4 + ii) * N + bn + c4) = o;
  }
}

// ---------------------------------------------------------------------------
// RoPE in-place on Q [B,S,32,128] and K0 [B,S,8,128].
// One thread per (row, head, i<64) pair handles elements i and i+64.
// ---------------------------------------------------------------------------
__global__ __launch_bounds__(256) void rope_kernel(float* __restrict__ Q,
                                                   float* __restrict__ K0) {
  const int per_row = (NH + NKV) * 64;  // 2560 pairs per (b,s) row
  int idx = blockIdx.x * 256 + threadIdx.x;
  if (idx >= MTOT * per_row) return;
  int row = idx / per_row;
  int rem = idx - row * per_row;
  int hh = rem >> 6;   // 0..39  (0..31 -> Q head, 32..39 -> K head)
  int i = rem & 63;    // 0..63
  int s = row & (SS - 1);

  // inv_freq = 10000^(-i/64) = exp(-i * ln(10000)/64)
  float invf = expf((float)i * (-9.210340371976184f / 64.0f));
  float ang = (float)s * invf;
  float cv = cosf(ang);
  float sv = sinf(ang);

  float* base;
  if (hh < NH)
    base = Q + (size_t)row * (NH * HD) + hh * HD;
  else
    base = K0 + (size_t)row * (NKV * HD) + (hh - NH) * HD;

  float x0 = base[i];
  float x1 = base[i + 64];
  base[i] = x0 * cv - x1 * sv;       // q*cos + rotate_half(q)*sin, d < 64
  base[i + 64] = x1 * cv + x0 * sv;  // d >= 64
}

// ---------------------------------------------------------------------------
// Attention: one block (128 threads) per (b, h, q).
// Q [B,S,32,128] (roped), K0/V0 [B,S,8,128] (K roped),
// k_suffix/v_suffix [B,8,3,S,128], out AO [B,S,32,128].
// Rows q >= valid are exactly zero (matches reference q_valid masking).
// ---------------------------------------------------------------------------
__global__ __launch_bounds__(128) void attn_kernel(
    const float* __restrict__ Q, const float* __restrict__ K0,
    const float* __restrict__ V0, const float* __restrict__ Ks,
    const float* __restrict__ Vs, float* __restrict__ O,
    const int* __restrict__ validp) {
  const int qi = blockIdx.x;
  const int h = blockIdx.y;
  const int b = blockIdx.z;
  const int t = threadIdx.x;
  const int valid = *validp;
  const int kvh = h >> 2;  // n_rep = 4

  float* orow = O + (size_t)(b * SS + qi) * (NH * HD) + h * HD;
  if (qi >= valid) {
    if (t < HD) orow[t] = 0.0f;
    return;
  }

  __shared__ float qs[HD];
  __shared__ float sc[SS + LCK];
  __shared__ float red[128];

  const float* qrow = Q + (size_t)(b * SS + qi) * (NH * HD) + h * HD;
  if (t < HD) qs[t] = qrow[t];
  __syncthreads();

  const float scale = 0.08838834764831845f;  // 1/sqrt(128)
  const int nk = qi + 1;                     // causal entries 0..qi (all valid: qi < valid)

  // causal scores
  for (int k = t; k < nk; k += 128) {
    const float* krow = K0 + (size_t)(b * SS + k) * (NKV * HD) + kvh * HD;
    float dot = 0.0f;
#pragma unroll 8
    for (int d = 0; d < HD; d += 4) {
      float4 kv = *(const float4*)(krow + d);
      dot += qs[d] * kv.x + qs[d + 1] * kv.y + qs[d + 2] * kv.z + qs[d + 3] * kv.w;
    }
    sc[k] = dot * scale;
  }
  // suffix scores: diagonal kv = q, un-roped K cache
  if (t < LCK) {
    const float* krow = Ks + (((size_t)(b * NKV + kvh) * LCK + t) * SS + qi) * HD;
    float dot = 0.0f;
#pragma unroll 8
    for (int d = 0; d < HD; ++d) dot += qs[d] * krow[d];
    sc[nk + t] = dot * scale;
  }
  __syncthreads();

  const int ntot = nk + LCK;
  // max
  float lm = -1e30f;
  for (int i = t; i < ntot; i += 128) lm = fmaxf(lm, sc[i]);
  red[t] = lm;
  __syncthreads();
#pragma unroll
  for (int s2 = 64; s2 > 0; s2 >>= 1) {
    if (t < s2) red[t] = fmaxf(red[t], red[t + s2]);
    __syncthreads();
  }
  const float m = red[0];
  __syncthreads();
  // exp + sum
  float ls = 0.0f;
  for (int i = t; i < ntot; i += 128) {
    float e = __expf(sc[i] - m);
    sc[i] = e;
    ls += e;
  }
  red[t] = ls;
  __syncthreads();
#pragma unroll
  for (int s2 = 64; s2 > 0; s2 >>= 1) {
    if (t < s2) red[t] += red[t + s2];
    __syncthreads();
  }
  const float inv = 1.0f / red[0];
  __syncthreads();

  // output: thread t = dim d, coalesced V reads
  const int d = t;  // blockDim == HD == 128
  float acc = 0.0f;
#pragma unroll 4
  for (int k = 0; k < nk; ++k) {
    acc += sc[k] * V0[(size_t)(b * SS + k) * (NKV * HD) + kvh * HD + d];
  }
#pragma unroll
  for (int j = 0; j < LCK; ++j) {
    acc += sc[nk + j] * Vs[(((size_t)(b * NKV + kvh) * LCK + j) * SS + qi) * HD + d];
  }
  orow[d] = acc * inv;
}

// ---------------------------------------------------------------------------
extern "C" void kernel_launch(void* const* d_in, const int* in_sizes, int n_in,
                              void* d_out, int out_size, void* d_ws, size_t ws_size,
                              hipStream_t stream) {
  const float* hidden = (const float*)d_in[0];
  const float* ksuf = (const float*)d_in[1];
  const float* vsuf = (const float*)d_in[2];
  const float* Wq = (const float*)d_in[3];
  const float* Wk = (const float*)d_in[4];
  const float* Wv = (const float*)d_in[5];
  const float* Wo = (const float*)d_in[6];
  const int* validp = (const int*)d_in[7];
  float* out = (float*)d_out;

  float* ws = (float*)d_ws;
  float* Q = ws;                                  // 2048*4096
  float* K0 = Q + (size_t)MTOT * NH * HD;         // 2048*1024
  float* V0 = K0 + (size_t)MTOT * NKV * HD;       // 2048*1024
  float* AO = V0 + (size_t)MTOT * NKV * HD;       // 2048*4096

  dim3 blk(256);
  // projections
  gemm_f32<<<dim3((NH * HD) / TILE, MTOT / TILE), blk, 0, stream>>>(
      hidden, Wq, Q, MTOT, NH * HD, HIDDEN);
  gemm_f32<<<dim3((NKV * HD) / TILE, MTOT / TILE), blk, 0, stream>>>(
      hidden, Wk, K0, MTOT, NKV * HD, HIDDEN);
  gemm_f32<<<dim3((NKV * HD) / TILE, MTOT / TILE), blk, 0, stream>>>(
      hidden, Wv, V0, MTOT, NKV * HD, HIDDEN);
  // RoPE on Q and K0
  {
    int total = MTOT * (NH + NKV) * 64;
    rope_kernel<<<(total + 255) / 256, 256, 0, stream>>>(Q, K0);
  }
  // attention
  attn_kernel<<<dim3(SS, NH, BB), dim3(128), 0, stream>>>(
      Q, K0, V0, ksuf, vsuf, AO, validp);
  // output projection
  gemm_f32<<<dim3(HIDDEN / TILE, MTOT / TILE), blk, 0, stream>>>(
      AO, Wo, out, MTOT, HIDDEN, HIDDEN);
}

// Round 2
// 735.690 us; speedup vs baseline: 6.5234x; 6.5234x over previous
//
#include <hip/hip_runtime.h>

#define HIDDEN 4096
#define NH 32
#define NKV 8
#define HD 128
#define LCK 3
#define BB 2
#define SS 1024
#define MTOT (BB * SS)  // 2048

typedef unsigned short u16;
typedef __attribute__((ext_vector_type(8))) short s16x8;   // 8 bf16 (4 VGPRs)
typedef __attribute__((ext_vector_type(4))) float f32x4;

__device__ __forceinline__ u16 f2bf(float f) {  // RNE float->bf16
  unsigned u = __builtin_bit_cast(unsigned, f);
  u += 0x7fffu + ((u >> 16) & 1u);
  return (u16)(u >> 16);
}
__device__ __forceinline__ float bf2f(u16 h) {
  return __builtin_bit_cast(float, (unsigned)h << 16);
}
// async global->LDS, 16B per lane; LDS dest = wave-uniform base + lane*16
__device__ __forceinline__ void gld16(const void* g, void* l) {
  __builtin_amdgcn_global_load_lds((const __attribute__((address_space(1))) void*)g,
                                   (__attribute__((address_space(3))) void*)l, 16, 0, 0);
}

// ---------------------------------------------------------------------------
// fp32 -> bf16 flat convert (hidden_states)
// ---------------------------------------------------------------------------
__global__ __launch_bounds__(256) void convert_h(const float* __restrict__ in,
                                                 u16* __restrict__ out, int n4) {
  int i = blockIdx.x * 256 + threadIdx.x;
  if (i >= n4) return;
  float4 v = ((const float4*)in)[i];
  uint2 o;
  o.x = (unsigned)f2bf(v.x) | ((unsigned)f2bf(v.y) << 16);
  o.y = (unsigned)f2bf(v.z) | ((unsigned)f2bf(v.w) << 16);
  ((uint2*)out)[i] = o;
}

// ---------------------------------------------------------------------------
// W [K][N] fp32  ->  Wt [N][K] bf16   (LDS tile transpose, 64x64)
// ---------------------------------------------------------------------------
__global__ __launch_bounds__(256) void transpose_w(const float* __restrict__ W,
                                                   u16* __restrict__ Wt, int K, int N) {
  __shared__ float tile[64][65];
  const int n0 = blockIdx.x * 64, k0 = blockIdx.y * 64;
  const int ty = threadIdx.x >> 6, tx = threadIdx.x & 63;
#pragma unroll
  for (int i = 0; i < 16; ++i) {
    int r = ty * 16 + i;
    tile[r][tx] = W[(size_t)(k0 + r) * N + n0 + tx];
  }
  __syncthreads();
#pragma unroll
  for (int i = 0; i < 16; ++i) {
    int r = ty * 16 + i;
    Wt[(size_t)(n0 + r) * K + k0 + tx] = f2bf(tile[tx][r]);
  }
}

// ---------------------------------------------------------------------------
// bf16 MFMA GEMM (m97 structure): C = A[M,K] @ Bt[N,K]^T
// 128x128 tile, BK=32, 256 threads (4 waves, each 64x64 = 4x4 16x16 tiles).
// LDS layout k-chunk-major [kc=4][row=128][8bf16] so frag reads are b128.
// C is split into up to 3 column-range destinations (fused QKV).
// ---------------------------------------------------------------------------
template <bool BF16OUT>
__global__ __launch_bounds__(256) void gemm_bt(
    const u16* __restrict__ A, const u16* __restrict__ Bt,
    void* C0v, void* C1v, void* C2v, int N, int K, int n1, int n2) {
  __shared__ u16 As[4][128][8];
  __shared__ u16 Bs[4][128][8];
  const int t = threadIdx.x, lane = t & 63, w = t >> 6;
  const int bm = blockIdx.y * 128, bn = blockIdx.x * 128;
  const int wm = (w >> 1) * 64, wn = (w & 1) * 64;
  const int col = lane & 15, quad = lane >> 4;

  f32x4 acc[4][4];
#pragma unroll
  for (int i = 0; i < 4; ++i)
#pragma unroll
    for (int j = 0; j < 4; ++j) acc[i][j] = (f32x4){0.f, 0.f, 0.f, 0.f};

  // staging: LDS byte o -> k-chunk c = o>>11, row r = (o>>4)&127
  const int o0 = w * 1024 + lane * 16;
  const int o1 = o0 + 4096;
  const int c0 = o0 >> 11, r0 = (o0 >> 4) & 127;
  const int c1 = o1 >> 11, r1 = (o1 >> 4) & 127;
  const u16* a0 = A + (size_t)(bm + r0) * K + c0 * 8;
  const u16* a1 = A + (size_t)(bm + r1) * K + c1 * 8;
  const u16* b0 = Bt + (size_t)(bn + r0) * K + c0 * 8;
  const u16* b1 = Bt + (size_t)(bn + r1) * K + c1 * 8;
  char* lA0 = (char*)As + w * 1024; char* lA1 = lA0 + 4096;
  char* lB0 = (char*)Bs + w * 1024; char* lB1 = lB0 + 4096;

  for (int k0 = 0; k0 < K; k0 += 32) {
    gld16(a0 + k0, lA0);
    gld16(a1 + k0, lA1);
    gld16(b0 + k0, lB0);
    gld16(b1 + k0, lB1);
    __syncthreads();
    s16x8 af[4], bfv[4];
#pragma unroll
    for (int i = 0; i < 4; ++i) af[i] = *(const s16x8*)&As[quad][wm + 16 * i + col][0];
#pragma unroll
    for (int j = 0; j < 4; ++j) bfv[j] = *(const s16x8*)&Bs[quad][wn + 16 * j + col][0];
#pragma unroll
    for (int i = 0; i < 4; ++i)
#pragma unroll
      for (int j = 0; j < 4; ++j)
        acc[i][j] = __builtin_amdgcn_mfma_f32_16x16x32_bf16(af[i], bfv[j], acc[i][j], 0, 0, 0);
    __syncthreads();
  }

  // epilogue: pick destination by column tile (wave-uniform)
  float* Cf; u16* Ch; int ldc, nb;
  if (bn < n1)      { ldc = n1;      nb = bn;      Cf = (float*)C0v; Ch = (u16*)C0v; }
  else if (bn < n2) { ldc = n2 - n1; nb = bn - n1; Cf = (float*)C1v; Ch = (u16*)C1v; }
  else              { ldc = N - n2;  nb = bn - n2; Cf = (float*)C2v; Ch = (u16*)C2v; }
#pragma unroll
  for (int i = 0; i < 4; ++i)
#pragma unroll
    for (int j = 0; j < 4; ++j)
#pragma unroll
      for (int r = 0; r < 4; ++r) {
        size_t off = (size_t)(bm + wm + 16 * i + quad * 4 + r) * ldc + nb + wn + 16 * j + col;
        if (BF16OUT) Ch[off] = f2bf(acc[i][j][r]);
        else         Cf[off] = acc[i][j][r];
      }
}

// ---------------------------------------------------------------------------
// RoPE + relayout: Qbf0 [b][s][32][128] -> Qbf [b][h][s][128] (bf16),
//                  K0bf [b][s][8][128]  -> Kbf [b][kvh][s][128]
// ---------------------------------------------------------------------------
__global__ __launch_bounds__(256) void rope_convert(const u16* __restrict__ Qin,
                                                    const u16* __restrict__ Kin,
                                                    u16* __restrict__ Qout,
                                                    u16* __restrict__ Kout) {
  const int per_row = (NH + NKV) * 64;  // 2560
  int idx = blockIdx.x * 256 + threadIdx.x;
  if (idx >= MTOT * per_row) return;
  int row = idx / per_row;          // b*1024 + s
  int rem = idx - row * per_row;
  int hh = rem >> 6, i = rem & 63;
  int s = row & (SS - 1), b = row >> 10;

  float invf = __expf((float)i * (-9.210340371976184f / 64.0f));
  float ang = (float)s * invf;
  float cv = cosf(ang), sv = sinf(ang);

  if (hh < NH) {
    const u16* src = Qin + (size_t)row * (NH * HD) + hh * HD;
    u16* dst = Qout + (((size_t)(b * NH + hh)) * SS + s) * HD;
    float x0 = bf2f(src[i]), x1 = bf2f(src[i + 64]);
    dst[i] = f2bf(x0 * cv - x1 * sv);
    dst[i + 64] = f2bf(x1 * cv + x0 * sv);
  } else {
    int kh = hh - NH;
    const u16* src = Kin + (size_t)row * (NKV * HD) + kh * HD;
    u16* dst = Kout + (((size_t)(b * NKV + kh)) * SS + s) * HD;
    float x0 = bf2f(src[i]), x1 = bf2f(src[i + 64]);
    dst[i] = f2bf(x0 * cv - x1 * sv);
    dst[i + 64] = f2bf(x1 * cv + x0 * sv);
  }
}

// ---------------------------------------------------------------------------
// V0bf [b][s][8][128] -> Vt [b][kvh][d=128][s=1024]  (bf16 tile transpose)
// ---------------------------------------------------------------------------
__global__ __launch_bounds__(256) void transpose_v(const u16* __restrict__ V0,
                                                   u16* __restrict__ Vt) {
  __shared__ u16 tile[64][65];
  const int s0 = blockIdx.x * 64, d0 = blockIdx.y * 64;
  const int bk = blockIdx.z;  // b*8 + kvh
  const int b = bk >> 3, kvh = bk & 7;
  const int ty = threadIdx.x >> 6, tx = threadIdx.x & 63;
#pragma unroll
  for (int i = 0; i < 16; ++i) {
    int r = ty * 16 + i;
    tile[r][tx] = V0[((size_t)(b * SS + s0 + r)) * (NKV * HD) + kvh * HD + d0 + tx];
  }
  __syncthreads();
#pragma unroll
  for (int i = 0; i < 16; ++i) {
    int r = ty * 16 + i;
    Vt[((size_t)bk * HD + d0 + r) * SS + s0 + tx] = tile[tx][r];
  }
}

// ---------------------------------------------------------------------------
// Flash MFMA attention.
// Block = (q-tile of 16, kvh, b); 4 waves = the 4 GQA heads of kvh.
// K-loop over 32-wide KV tiles: QK^T (mfma 16x16x32) -> online softmax in
// C-layout registers (state rows == C rows, no LDS state) -> P to LDS (bf16)
// -> PV (mfma). 3 suffix diagonal blocks folded in via fp32 epilogue.
// Output AObf [b][s][h][d] bf16, rows q>=valid zeroed.
// ---------------------------------------------------------------------------
__global__ __launch_bounds__(256) void attn_mfma(
    const u16* __restrict__ Qbf, const u16* __restrict__ Kbf, const u16* __restrict__ Vt,
    const float* __restrict__ ksuf, const float* __restrict__ vsuf,
    u16* __restrict__ AObf, const int* __restrict__ validp) {
  __shared__ u16 Ksh[16][32][8];    // [d-chunk][k-row][8]  8KB
  __shared__ u16 Vsh[4][128][8];    // [k-chunk][d][8]      8KB
  __shared__ u16 Psh[4][4][16][8];  // [wave][k-chunk][q-row][8] 4KB

  const int qt = 63 - (int)blockIdx.x;  // heavy q-tiles dispatched first
  const int q0 = qt * 16;
  const int kvh = blockIdx.y, b = blockIdx.z;
  const int t = threadIdx.x, lane = t & 63, w = t >> 6;
  const int col = lane & 15, quad = lane >> 4;
  const int h = (kvh << 2) + w;
  const int valid = *validp;

  size_t obase = ((size_t)(b * SS + q0 + quad * 4)) * (NH * HD) + h * HD + col;
  if (q0 >= valid) {
#pragma unroll
    for (int r = 0; r < 4; ++r) {
      size_t o = obase + (size_t)r * (NH * HD);
#pragma unroll
      for (int nt = 0; nt < 8; ++nt) AObf[o + 16 * nt] = 0;
    }
    return;
  }

  const float scale = 0.08838834764831845f;  // 1/sqrt(128)
  // Q fragments (A-operand, loop-invariant): lane holds Q[q0+col][quad*8.. per ds]
  const u16* qptr = Qbf + (((size_t)(b * NH + h)) * SS + q0 + col) * HD;
  s16x8 qf[4];
#pragma unroll
  for (int ds = 0; ds < 4; ++ds) qf[ds] = *(const s16x8*)(qptr + ds * 32 + quad * 8);

  const u16* kbase = Kbf + ((size_t)(b * NKV + kvh)) * SS * HD;
  const u16* vbase = Vt + ((size_t)(b * NKV + kvh)) * HD * SS;

  float m_[4], l_[4];
  f32x4 O_[8];
#pragma unroll
  for (int r = 0; r < 4; ++r) { m_[r] = -1e30f; l_[r] = 0.f; }
#pragma unroll
  for (int nt = 0; nt < 8; ++nt) O_[nt] = (f32x4){0.f, 0.f, 0.f, 0.f};

  const int ntiles = (q0 + 47) >> 5;
  const int o0 = w * 1024 + lane * 16;
  const int o1 = o0 + 4096;

  for (int ti = 0; ti < ntiles; ++ti) {
    const int k0 = ti * 32;
    {  // stage K-tile and V^T-tile via global_load_lds (16B/lane)
      int dc = o0 >> 9, kr = (o0 >> 4) & 31;
      gld16(kbase + (size_t)(k0 + kr) * HD + dc * 8, (char*)Ksh + w * 1024);
      dc = o1 >> 9; kr = (o1 >> 4) & 31;
      gld16(kbase + (size_t)(k0 + kr) * HD + dc * 8, (char*)Ksh + w * 1024 + 4096);
      int kc = o0 >> 11, d = (o0 >> 4) & 127;
      gld16(vbase + (size_t)d * SS + k0 + kc * 8, (char*)Vsh + w * 1024);
      kc = o1 >> 11; d = (o1 >> 4) & 127;
      gld16(vbase + (size_t)d * SS + k0 + kc * 8, (char*)Vsh + w * 1024 + 4096);
    }
    __syncthreads();

    // QK^T: two 16-col subtiles
    f32x4 S0 = (f32x4){0.f,0.f,0.f,0.f}, S1 = (f32x4){0.f,0.f,0.f,0.f};
#pragma unroll
    for (int ds = 0; ds < 4; ++ds) {
      s16x8 kf0 = *(const s16x8*)&Ksh[ds * 4 + quad][col][0];
      s16x8 kf1 = *(const s16x8*)&Ksh[ds * 4 + quad][col + 16][0];
      S0 = __builtin_amdgcn_mfma_f32_16x16x32_bf16(qf[ds], kf0, S0, 0, 0, 0);
      S1 = __builtin_amdgcn_mfma_f32_16x16x32_bf16(qf[ds], kf1, S1, 0, 0, 0);
    }

    // online softmax update (rows = quad*4+r, cols across 16 lanes)
    float al[4], p0v[4], p1v[4];
#pragma unroll
    for (int r = 0; r < 4; ++r) {
      int row_g = q0 + quad * 4 + r;
      float s0 = (k0 + col > row_g) ? -1e30f : S0[r] * scale;
      float s1 = (k0 + 16 + col > row_g) ? -1e30f : S1[r] * scale;
      float tm = fmaxf(s0, s1);
      tm = fmaxf(tm, __shfl_xor(tm, 1));
      tm = fmaxf(tm, __shfl_xor(tm, 2));
      tm = fmaxf(tm, __shfl_xor(tm, 4));
      tm = fmaxf(tm, __shfl_xor(tm, 8));
      float mn = fmaxf(m_[r], tm);
      float a = __expf(m_[r] - mn);
      float p0 = __expf(s0 - mn), p1 = __expf(s1 - mn);
      float rs = p0 + p1;
      rs += __shfl_xor(rs, 1);
      rs += __shfl_xor(rs, 2);
      rs += __shfl_xor(rs, 4);
      rs += __shfl_xor(rs, 8);
      l_[r] = l_[r] * a + rs;
      m_[r] = mn;
      al[r] = a; p0v[r] = p0; p1v[r] = p1;
    }
#pragma unroll
    for (int nt = 0; nt < 8; ++nt)
#pragma unroll
      for (int r = 0; r < 4; ++r) O_[nt][r] *= al[r];

    // P (C-layout) -> LDS in A-operand-friendly chunked layout
    {
      int kcA = col >> 3, kk = col & 7;
#pragma unroll
      for (int r = 0; r < 4; ++r) {
        Psh[w][kcA][quad * 4 + r][kk] = f2bf(p0v[r]);
        Psh[w][2 + kcA][quad * 4 + r][kk] = f2bf(p1v[r]);
      }
    }
    __syncthreads();

    // PV: O[16][128] += P[16][32] @ V[32][128]
    s16x8 pf = *(const s16x8*)&Psh[w][quad][col][0];
#pragma unroll
    for (int nt = 0; nt < 8; ++nt) {
      s16x8 vf = *(const s16x8*)&Vsh[quad][col + 16 * nt][0];
      O_[nt] = __builtin_amdgcn_mfma_f32_16x16x32_bf16(pf, vf, O_[nt], 0, 0, 0);
    }
    __syncthreads();
  }

  // ---- suffix blocks (diagonal kv = q), fp32, folded into online softmax ----
  float sr[3][4];
#pragma unroll
  for (int j = 0; j < 3; ++j) {
    const float* krow = ksuf + ((((size_t)(b * NKV + kvh) * LCK + j)) * SS + q0 + col) * HD;
    float p = 0.f;
#pragma unroll
    for (int ds = 0; ds < 4; ++ds) {
      const float* kp = krow + ds * 32 + quad * 8;
#pragma unroll
      for (int e = 0; e < 8; ++e) p += bf2f((u16)qf[ds][e]) * kp[e];
    }
    p += __shfl_xor(p, 16);
    p += __shfl_xor(p, 32);
    p *= scale;
#pragma unroll
    for (int r = 0; r < 4; ++r) sr[j][r] = __shfl(p, quad * 4 + r);
  }
#pragma unroll
  for (int r = 0; r < 4; ++r) {
    int q = q0 + quad * 4 + r;
    float ms = fmaxf(fmaxf(sr[0][r], sr[1][r]), sr[2][r]);
    float mn = fmaxf(m_[r], ms);
    float a = __expf(m_[r] - mn);
    float p0 = __expf(sr[0][r] - mn);
    float p1 = __expf(sr[1][r] - mn);
    float p2 = __expf(sr[2][r] - mn);
    l_[r] = l_[r] * a + p0 + p1 + p2;
    const float* v0r = vsuf + ((((size_t)(b * NKV + kvh) * LCK + 0)) * SS + q) * HD + col;
    const float* v1r = v0r + (size_t)SS * HD;
    const float* v2r = v1r + (size_t)SS * HD;
#pragma unroll
    for (int nt = 0; nt < 8; ++nt)
      O_[nt][r] = O_[nt][r] * a + p0 * v0r[16 * nt] + p1 * v1r[16 * nt] + p2 * v2r[16 * nt];
    m_[r] = mn;
  }

  // ---- write AObf [b][s][h][d] (bf16); rows >= valid are zero ----
#pragma unroll
  for (int r = 0; r < 4; ++r) {
    int q = q0 + quad * 4 + r;
    size_t o = obase + (size_t)r * (NH * HD);
    if (q >= valid) {
#pragma unroll
      for (int nt = 0; nt < 8; ++nt) AObf[o + 16 * nt] = 0;
    } else {
      float inv = 1.f / l_[r];
#pragma unroll
      for (int nt = 0; nt < 8; ++nt) AObf[o + 16 * nt] = f2bf(O_[nt][r] * inv);
    }
  }
}

// ---------------------------------------------------------------------------
extern "C" void kernel_launch(void* const* d_in, const int* in_sizes, int n_in,
                              void* d_out, int out_size, void* d_ws, size_t ws_size,
                              hipStream_t stream) {
  const float* hidden = (const float*)d_in[0];
  const float* ksuf = (const float*)d_in[1];
  const float* vsuf = (const float*)d_in[2];
  const float* Wq = (const float*)d_in[3];
  const float* Wk = (const float*)d_in[4];
  const float* Wv = (const float*)d_in[5];
  const float* Wo = (const float*)d_in[6];
  const int* validp = (const int*)d_in[7];
  float* out = (float*)d_out;

  // workspace layout (96MB peak, regions aliased across phases)
  char* W = (char*)d_ws;
  u16* Hbf  = (u16*)(W + 0);                     // 16MB  (dead after QKV gemm)
  u16* WqT  = (u16*)(W + ((size_t)16 << 20));    // 32MB  (WqT|WkT|WvT contiguous [6144][4096])
  u16* WkT  = (u16*)(W + ((size_t)48 << 20));    // 8MB
  u16* WvT  = (u16*)(W + ((size_t)56 << 20));    // 8MB
  u16* Qbf0 = (u16*)(W + ((size_t)64 << 20));    // 16MB  (dead after rope)
  u16* K0bf = (u16*)(W + ((size_t)80 << 20));    // 4MB
  u16* V0bf = (u16*)(W + ((size_t)84 << 20));    // 4MB
  u16* Kbf  = (u16*)(W + ((size_t)88 << 20));    // 4MB
  u16* Vt   = (u16*)(W + ((size_t)92 << 20));    // 4MB
  u16* Qbf  = (u16*)(W + 0);                     // alias Hbf
  u16* WoT  = (u16*)(W + ((size_t)16 << 20));    // alias WqT
  u16* AObf = (u16*)(W + ((size_t)64 << 20));    // alias Qbf0

  // 1. convert hidden -> bf16
  convert_h<<<(MTOT * HIDDEN / 4 + 255) / 256, 256, 0, stream>>>(hidden, Hbf, MTOT * HIDDEN / 4);
  // 2. transpose+convert projection weights (B^T for gemm)
  transpose_w<<<dim3(64, 64), 256, 0, stream>>>(Wq, WqT, HIDDEN, NH * HD);
  transpose_w<<<dim3(16, 64), 256, 0, stream>>>(Wk, WkT, HIDDEN, NKV * HD);
  transpose_w<<<dim3(16, 64), 256, 0, stream>>>(Wv, WvT, HIDDEN, NKV * HD);
  // 3. fused QKV projection: N = 4096+1024+1024, bf16 out
  gemm_bt<true><<<dim3(48, 16), 256, 0, stream>>>(
      Hbf, WqT, Qbf0, K0bf, V0bf, 6144, HIDDEN, 4096, 5120);
  // 4. Wo transpose (into dead WqT region)
  transpose_w<<<dim3(64, 64), 256, 0, stream>>>(Wo, WoT, NH * HD, HIDDEN);
  // 5. RoPE + head-major relayout (Qbf over dead Hbf)
  rope_convert<<<(MTOT * (NH + NKV) * 64 + 255) / 256, 256, 0, stream>>>(Qbf0, K0bf, Qbf, Kbf);
  // 6. V transpose to [b][kvh][d][s]
  transpose_v<<<dim3(16, 2, BB * NKV), 256, 0, stream>>>(V0bf, Vt);
  // 7. flash MFMA attention (AObf over dead Qbf0)
  attn_mfma<<<dim3(64, NKV, BB), 256, 0, stream>>>(Qbf, Kbf, Vt, ksuf, vsuf, AObf, validp);
  // 8. output projection (fp32 out)
  gemm_bt<false><<<dim3(32, 16), 256, 0, stream>>>(
      AObf, WoT, out, out, out, HIDDEN, NH * HD, 4096, 4096);
}